// Round 11
// baseline (163.435 us; speedup 1.0000x reference)
//
#include <hip/hip_runtime.h>
#include <hip/hip_bf16.h>

#define B_  8
#define S_  2048
#define D_  1024
#define E_  16
#define SD_ 64
#define SH_ 256
#define H_  4096
#define R_  (D_ * S_)      // 2097152 rows of w_switch (MAX_SEQ == S)
#define NBLK_ 8192         // router blocks (burst-style: 256 rows/block)

typedef __attribute__((ext_vector_type(8))) short bf16x8;
typedef __attribute__((ext_vector_type(4))) float f32x4;

static __device__ __forceinline__ short f2bf(float f) {
    union { float f; unsigned u; } v; v.f = f;
    unsigned r = v.u + 0x7fffu + ((v.u >> 16) & 1u);   // RNE to bf16
    return (short)(r >> 16);
}

// ---------------------------------------------------------------------------
// Convert w1 [16][64][256] + w2 [4096][1024] fp32 -> MFMA B-fragment bf16.
// Blocks [0,128): w1; blocks [128,2176): w2.
// ---------------------------------------------------------------------------
__global__ void convert_w(const float* __restrict__ w1, const float* __restrict__ w2,
                          short* __restrict__ w1f, short* __restrict__ w2f) {
    int blk = blockIdx.x;
    if (blk < 128) {
        int t = blk * 256 + threadIdx.x;              // 32768 threads
        int lane = t & 63, ntile = (t >> 6) & 15, ks = (t >> 10) & 1, e = t >> 11;
        int k0 = ks * 32 + ((lane >> 4) << 3);
        int n  = (ntile << 4) + (lane & 15);
        const float* src = w1 + ((size_t)(e * 64 + k0) * 256 + n);
        bf16x8 o;
        #pragma unroll
        for (int j = 0; j < 8; ++j) o[j] = f2bf(src[(size_t)j * 256]);
        *(bf16x8*)(w1f + ((size_t)t << 3)) = o;
    } else {
        int t = (blk - 128) * 256 + threadIdx.x;      // 524288 threads
        int lane = t & 63, ntile = (t >> 6) & 63, kg = t >> 12;   // kg < 128
        int k0 = (kg << 5) + ((lane >> 4) << 3);
        int n  = (ntile << 4) + (lane & 15);
        const float* src = w2 + ((size_t)k0 * 1024 + n);
        bf16x8 o;
        #pragma unroll
        for (int j = 0; j < 8; ++j) o[j] = f2bf(src[(size_t)j * 1024]);
        *(bf16x8*)(w2f + ((size_t)t << 3)) = o;
    }
}

// ---------------------------------------------------------------------------
// Router, burst-style (R7, best-known at 78.8 µs): wave owns 64 rows; all 36
// loads (4 w-float4 + 32 x-scalars) issue as one independent burst, then
// 128 FMAs, shuffle-reduce, ONE CONTIGUOUS 512-B partial write per block
// (partials transposed to [block][entry] to kill the scattered-line writes).
// ---------------------------------------------------------------------------
__global__ __launch_bounds__(256, 4) void router_kernel(const float* __restrict__ x,
                                                        const float* __restrict__ wsw,
                                                        float* __restrict__ partials) {
    __shared__ float red[512];
    int tid = threadIdx.x;
    int wid = tid >> 6, lane = tid & 63;
    int q = lane & 3, rsub = lane >> 2;                // row within 16
    size_t wavebase = (((size_t)blockIdx.x << 2) + wid) << 6;   // 64 rows/wave
    const f32x4* wp = (const f32x4*)wsw + (wavebase << 2) + lane;

    // ---- burst loads: all independent ----
    f32x4 w0 = wp[0];
    f32x4 w1v = wp[64];
    f32x4 w2v = wp[128];
    f32x4 w3v = wp[192];
    float xv[4][8];
    #pragma unroll
    for (int b = 0; b < 8; ++b) {
        const float* xb = x + (size_t)b * R_ + wavebase + rsub;
        #pragma unroll
        for (int it = 0; it < 4; ++it)
            xv[it][b] = xb[it << 4];
    }

    // ---- compute ----
    float acc[8][4];
    #pragma unroll
    for (int b = 0; b < 8; ++b)
        #pragma unroll
        for (int j = 0; j < 4; ++j) acc[b][j] = 0.f;

    #define FMA4(W, IT)                                             \
        _Pragma("unroll")                                           \
        for (int b = 0; b < 8; ++b) {                               \
            float xs = xv[IT][b];                                   \
            acc[b][0] = fmaf(xs, (W)[0], acc[b][0]);                \
            acc[b][1] = fmaf(xs, (W)[1], acc[b][1]);                \
            acc[b][2] = fmaf(xs, (W)[2], acc[b][2]);                \
            acc[b][3] = fmaf(xs, (W)[3], acc[b][3]);                \
        }
    FMA4(w0, 0)
    FMA4(w1v, 1)
    FMA4(w2v, 2)
    FMA4(w3v, 3)
    #undef FMA4

    // reduce across the 16 lanes sharing q (xor 4,8,16,32)
    #pragma unroll
    for (int b = 0; b < 8; ++b)
        #pragma unroll
        for (int j = 0; j < 4; ++j) {
            float v = acc[b][j];
            v += __shfl_xor(v, 4);
            v += __shfl_xor(v, 8);
            v += __shfl_xor(v, 16);
            v += __shfl_xor(v, 32);
            acc[b][j] = v;
        }

    if (lane < 4) {
        #pragma unroll
        for (int b = 0; b < 8; ++b)
            #pragma unroll
            for (int j = 0; j < 4; ++j)
                red[(wid << 7) + b * 16 + q * 4 + j] = acc[b][j];
    }
    __syncthreads();
    if (tid < 128)
        partials[(size_t)blockIdx.x * 128 + tid] =
            red[tid] + red[128 + tid] + red[256 + tid] + red[384 + tid];
}

// ---------------------------------------------------------------------------
// Reduce partials[8192][128] -> logits[128]. Block e sums column e.
// ---------------------------------------------------------------------------
__global__ __launch_bounds__(256) void reduce_kernel(const float* __restrict__ partials,
                                                     float* __restrict__ logits) {
    __shared__ float s[256];
    int e = blockIdx.x, tid = threadIdx.x;
    float t = 0.f;
    #pragma unroll
    for (int k = 0; k < 32; ++k)
        t += partials[(size_t)(tid + (k << 8)) * 128 + e];
    s[tid] = t;
    __syncthreads();
    #pragma unroll
    for (int off = 128; off; off >>= 1) {
        if (tid < off) s[tid] += s[tid + off];
        __syncthreads();
    }
    if (tid == 0) logits[e] = s[0];
}

// ---------------------------------------------------------------------------
// Top-2 per batch (softmax is monotone). Ties -> lower index.
// ---------------------------------------------------------------------------
__global__ void topk_kernel(const float* __restrict__ logits,
                            const float* __restrict__ bsw,
                            int* __restrict__ experts) {
    int b = threadIdx.x;
    if (b >= 8) return;
    float v[16];
    #pragma unroll
    for (int e = 0; e < 16; ++e) v[e] = logits[b * 16 + e] + bsw[e];
    int i0 = 0; float m0 = v[0];
    #pragma unroll
    for (int e = 1; e < 16; ++e) if (v[e] > m0) { m0 = v[e]; i0 = e; }
    int i1 = -1; float m1 = -3.4e38f;
    #pragma unroll
    for (int e = 0; e < 16; ++e) if (e != i0 && v[e] > m1) { m1 = v[e]; i1 = e; }
    experts[2 * b]     = i0;
    experts[2 * b + 1] = i1;
}

// ---------------------------------------------------------------------------
// Fused expert MLP — verified structure, re-tiled to 16 tokens/block
// (m-loop deleted), 1024 blocks, 3 blocks/CU for more write-phase TLP.
// ---------------------------------------------------------------------------
__global__ __launch_bounds__(256, 3) void mlp_kernel(
        const float* __restrict__ x, const int* __restrict__ experts,
        const short* __restrict__ w1f, const float* __restrict__ b1,
        const short* __restrict__ w2f, const float* __restrict__ b2,
        float* __restrict__ out) {
    __shared__ short G[16][520];

    int blk  = blockIdx.x;
    int b    = blk & 7;            // XCD-friendly: batch = blk%8
    int tok0 = (blk >> 3) << 4;    // 16-token tile, tile = blk>>3 in [0,128)
    int e0 = experts[2 * b], e1 = experts[2 * b + 1];
    int tid = threadIdx.x;
    int wid = tid >> 6, lane = tid & 63;
    int slot  = wid >> 1;
    int ex    = slot ? e1 : e0;
    int nhalf = wid & 1;
    int lrow = lane & 15, lk8 = (lane >> 4) << 3;
    int r0 = (lane >> 4) << 2;

    f32x4 acc1[8];
    #pragma unroll
    for (int n = 0; n < 8; ++n) acc1[n] = (f32x4){0.f, 0.f, 0.f, 0.f};

    #pragma unroll
    for (int ks = 0; ks < 2; ++ks) {
        const float* xp = x + (((size_t)b * S_ + tok0 + lrow) * D_
                               + ex * 64 + ks * 32 + lk8);
        float4 f0 = *(const float4*)xp;
        float4 f1 = *(const float4*)(xp + 4);
        bf16x8 a;
        a[0] = f2bf(f0.x); a[1] = f2bf(f0.y); a[2] = f2bf(f0.z); a[3] = f2bf(f0.w);
        a[4] = f2bf(f1.x); a[5] = f2bf(f1.y); a[6] = f2bf(f1.z); a[7] = f2bf(f1.w);
        #pragma unroll
        for (int nt = 0; nt < 8; ++nt) {
            int ntg = nhalf * 8 + nt;
            bf16x8 bf = *(const bf16x8*)(w1f + ((((size_t)(ex * 2 + ks) * 16 + ntg) * 64 + lane) << 3));
            acc1[nt] = __builtin_amdgcn_mfma_f32_16x16x32_bf16(a, bf, acc1[nt], 0, 0, 0);
        }
    }

    #pragma unroll
    for (int nt = 0; nt < 8; ++nt) {
        int ncol = (nhalf * 8 + nt) * 16 + lrow;
        float bb = b1[ex * 256 + ncol];
        #pragma unroll
        for (int r = 0; r < 4; ++r) {
            float v = acc1[nt][r] + bb;
            v = 0.5f * v * (1.0f + erff(v * 0.70710678118f));
            G[r0 + r][slot * 256 + ncol] = f2bf(v);
        }
    }
    __syncthreads();

    f32x4 acc2[16];
    #pragma unroll
    for (int n = 0; n < 16; ++n) acc2[n] = (f32x4){0.f, 0.f, 0.f, 0.f};

    for (int ks = 0; ks < 16; ++ks) {
        int e  = (ks < 8) ? e0 : e1;
        int kg = e * 8 + (ks & 7);
        bf16x8 a0 = *(const bf16x8*)&G[lrow][ks * 32 + lk8];
        #pragma unroll
        for (int nt = 0; nt < 16; ++nt) {
            int ntg = wid * 16 + nt;
            bf16x8 bf = *(const bf16x8*)(w2f + ((((size_t)kg * 64 + ntg) * 64 + lane) << 3));
            acc2[nt] = __builtin_amdgcn_mfma_f32_16x16x32_bf16(a0, bf, acc2[nt], 0, 0, 0);
        }
    }

    size_t obase = ((size_t)b * S_ + tok0) * D_;
    #pragma unroll
    for (int nt = 0; nt < 16; ++nt) {
        int d = wid * 256 + nt * 16 + lrow;
        float bb = b2[d];
        #pragma unroll
        for (int r = 0; r < 4; ++r)
            out[obase + (size_t)(r0 + r) * D_ + d] = acc2[nt][r] + bb;
    }
}

// ---------------------------------------------------------------------------
extern "C" void kernel_launch(void* const* d_in, const int* in_sizes, int n_in,
                              void* d_out, int out_size, void* d_ws, size_t ws_size,
                              hipStream_t stream) {
    const float* x   = (const float*)d_in[0];
    const float* wsw = (const float*)d_in[1];
    const float* bsw = (const float*)d_in[2];
    const float* w1  = (const float*)d_in[3];
    const float* b1  = (const float*)d_in[4];
    const float* w2  = (const float*)d_in[5];
    const float* b2  = (const float*)d_in[6];
    float* out = (float*)d_out;

    int*   experts  = (int*)d_ws;                                    // 64 B
    float* logits   = (float*)((char*)d_ws + 512);                   // 512 B
    float* partials = (float*)((char*)d_ws + 4096);                  // 8192*128*4 = 4 MB
    short* w1f = (short*)((char*)d_ws + 4096 + 4194304);             // 512 KB
    short* w2f = (short*)((char*)d_ws + 4096 + 4194304 + 524288);    // 8 MB

    router_kernel<<<NBLK_, 256, 0, stream>>>(x, wsw, partials);
    convert_w<<<2176, 256, 0, stream>>>(w1, w2, w1f, w2f);
    reduce_kernel<<<128, 256, 0, stream>>>(partials, logits);
    topk_kernel<<<1, 64, 0, stream>>>(logits, bsw, experts);
    mlp_kernel<<<1024, 256, 0, stream>>>(x, experts, w1f, b1, w2f, b2, out);
}

// Round 12
// 138.002 us; speedup vs baseline: 1.1843x; 1.1843x over previous
//
#include <hip/hip_runtime.h>
#include <hip/hip_bf16.h>

#define B_  8
#define S_  2048
#define D_  1024
#define E_  16
#define SD_ 64
#define SH_ 256
#define H_  4096
#define R_  (D_ * S_)      // 2097152 rows of w_switch (MAX_SEQ == S)
#define NBLK_ 8192         // router blocks (burst-style: 256 rows/block)

typedef __attribute__((ext_vector_type(8))) short bf16x8;
typedef __attribute__((ext_vector_type(4))) float f32x4;

static __device__ __forceinline__ short f2bf(float f) {
    union { float f; unsigned u; } v; v.f = f;
    unsigned r = v.u + 0x7fffu + ((v.u >> 16) & 1u);   // RNE to bf16
    return (short)(r >> 16);
}

// ---------------------------------------------------------------------------
// Convert w1 [16][64][256] + w2 [4096][1024] fp32 -> MFMA B-fragment bf16.
// Blocks [0,128): w1; blocks [128,2176): w2.
// ---------------------------------------------------------------------------
__global__ void convert_w(const float* __restrict__ w1, const float* __restrict__ w2,
                          short* __restrict__ w1f, short* __restrict__ w2f) {
    int blk = blockIdx.x;
    if (blk < 128) {
        int t = blk * 256 + threadIdx.x;              // 32768 threads
        int lane = t & 63, ntile = (t >> 6) & 15, ks = (t >> 10) & 1, e = t >> 11;
        int k0 = ks * 32 + ((lane >> 4) << 3);
        int n  = (ntile << 4) + (lane & 15);
        const float* src = w1 + ((size_t)(e * 64 + k0) * 256 + n);
        bf16x8 o;
        #pragma unroll
        for (int j = 0; j < 8; ++j) o[j] = f2bf(src[(size_t)j * 256]);
        *(bf16x8*)(w1f + ((size_t)t << 3)) = o;
    } else {
        int t = (blk - 128) * 256 + threadIdx.x;      // 524288 threads
        int lane = t & 63, ntile = (t >> 6) & 63, kg = t >> 12;   // kg < 128
        int k0 = (kg << 5) + ((lane >> 4) << 3);
        int n  = (ntile << 4) + (lane & 15);
        const float* src = w2 + ((size_t)k0 * 1024 + n);
        bf16x8 o;
        #pragma unroll
        for (int j = 0; j < 8; ++j) o[j] = f2bf(src[(size_t)j * 1024]);
        *(bf16x8*)(w2f + ((size_t)t << 3)) = o;
    }
}

// ---------------------------------------------------------------------------
// Router, burst-style (R7 shape + R11 contiguous partial writes):
// wave owns 64 rows; all 36 loads (4 w-float4 + 32 x-64B-lines) issue as one
// independent burst, then 128 FMAs, shuffle-reduce, ONE contiguous 512-B
// partial write per block. partials layout: [block][entry(128)]
// ---------------------------------------------------------------------------
__global__ __launch_bounds__(256, 4) void router_kernel(const float* __restrict__ x,
                                                        const float* __restrict__ wsw,
                                                        float* __restrict__ partials) {
    __shared__ float red[512];
    int tid = threadIdx.x;
    int wid = tid >> 6, lane = tid & 63;
    int q = lane & 3, rsub = lane >> 2;                // row within 16
    size_t wavebase = (((size_t)blockIdx.x << 2) + wid) << 6;   // 64 rows/wave
    const f32x4* wp = (const f32x4*)wsw + (wavebase << 2) + lane;

    // ---- burst loads: all independent ----
    f32x4 w0 = wp[0];
    f32x4 w1v = wp[64];
    f32x4 w2v = wp[128];
    f32x4 w3v = wp[192];
    float xv[4][8];
    #pragma unroll
    for (int b = 0; b < 8; ++b) {
        const float* xb = x + (size_t)b * R_ + wavebase + rsub;
        #pragma unroll
        for (int it = 0; it < 4; ++it)
            xv[it][b] = xb[it << 4];
    }

    // ---- compute ----
    float acc[8][4];
    #pragma unroll
    for (int b = 0; b < 8; ++b)
        #pragma unroll
        for (int j = 0; j < 4; ++j) acc[b][j] = 0.f;

    #define FMA4(W, IT)                                             \
        _Pragma("unroll")                                           \
        for (int b = 0; b < 8; ++b) {                               \
            float xs = xv[IT][b];                                   \
            acc[b][0] = fmaf(xs, (W)[0], acc[b][0]);                \
            acc[b][1] = fmaf(xs, (W)[1], acc[b][1]);                \
            acc[b][2] = fmaf(xs, (W)[2], acc[b][2]);                \
            acc[b][3] = fmaf(xs, (W)[3], acc[b][3]);                \
        }
    FMA4(w0, 0)
    FMA4(w1v, 1)
    FMA4(w2v, 2)
    FMA4(w3v, 3)
    #undef FMA4

    // reduce across the 16 lanes sharing q (xor 4,8,16,32)
    #pragma unroll
    for (int b = 0; b < 8; ++b)
        #pragma unroll
        for (int j = 0; j < 4; ++j) {
            float v = acc[b][j];
            v += __shfl_xor(v, 4);
            v += __shfl_xor(v, 8);
            v += __shfl_xor(v, 16);
            v += __shfl_xor(v, 32);
            acc[b][j] = v;
        }

    if (lane < 4) {
        #pragma unroll
        for (int b = 0; b < 8; ++b)
            #pragma unroll
            for (int j = 0; j < 4; ++j)
                red[(wid << 7) + b * 16 + q * 4 + j] = acc[b][j];
    }
    __syncthreads();
    if (tid < 128)
        partials[(size_t)blockIdx.x * 128 + tid] =
            red[tid] + red[128 + tid] + red[256 + tid] + red[384 + tid];
}

// ---------------------------------------------------------------------------
// Reduce partials[8192][128] -> logits[128]. Block e sums column e.
// ---------------------------------------------------------------------------
__global__ __launch_bounds__(256) void reduce_kernel(const float* __restrict__ partials,
                                                     float* __restrict__ logits) {
    __shared__ float s[256];
    int e = blockIdx.x, tid = threadIdx.x;
    float t = 0.f;
    #pragma unroll
    for (int k = 0; k < 32; ++k)
        t += partials[(size_t)(tid + (k << 8)) * 128 + e];
    s[tid] = t;
    __syncthreads();
    #pragma unroll
    for (int off = 128; off; off >>= 1) {
        if (tid < off) s[tid] += s[tid + off];
        __syncthreads();
    }
    if (tid == 0) logits[e] = s[0];
}

// ---------------------------------------------------------------------------
// Top-2 per batch (softmax is monotone). Ties -> lower index.
// ---------------------------------------------------------------------------
__global__ void topk_kernel(const float* __restrict__ logits,
                            const float* __restrict__ bsw,
                            int* __restrict__ experts) {
    int b = threadIdx.x;
    if (b >= 8) return;
    float v[16];
    #pragma unroll
    for (int e = 0; e < 16; ++e) v[e] = logits[b * 16 + e] + bsw[e];
    int i0 = 0; float m0 = v[0];
    #pragma unroll
    for (int e = 1; e < 16; ++e) if (v[e] > m0) { m0 = v[e]; i0 = e; }
    int i1 = -1; float m1 = -3.4e38f;
    #pragma unroll
    for (int e = 0; e < 16; ++e) if (e != i0 && v[e] > m1) { m1 = v[e]; i1 = e; }
    experts[2 * b]     = i0;
    experts[2 * b + 1] = i1;
}

// ---------------------------------------------------------------------------
// Fused expert MLP — exact R8 version (verified fast, absmax 0.0078):
// 32 tokens/block, 512 blocks, each w2f fragment load feeds 2 MFMAs.
// ---------------------------------------------------------------------------
__global__ __launch_bounds__(256, 2) void mlp_kernel(
        const float* __restrict__ x, const int* __restrict__ experts,
        const short* __restrict__ w1f, const float* __restrict__ b1,
        const short* __restrict__ w2f, const float* __restrict__ b2,
        float* __restrict__ out) {
    __shared__ short G[32][520];

    int blk  = blockIdx.x;
    int b    = blk & 7;            // XCD-friendly: batch = blk%8
    int tok0 = (blk >> 3) << 5;
    int e0 = experts[2 * b], e1 = experts[2 * b + 1];
    int tid = threadIdx.x;
    int wid = tid >> 6, lane = tid & 63;
    int slot  = wid >> 1;
    int ex    = slot ? e1 : e0;
    int nhalf = wid & 1;
    int lrow = lane & 15, lk8 = (lane >> 4) << 3;

    f32x4 acc1[2][8];
    #pragma unroll
    for (int m = 0; m < 2; ++m)
        #pragma unroll
        for (int n = 0; n < 8; ++n) acc1[m][n] = (f32x4){0.f, 0.f, 0.f, 0.f};

    #pragma unroll
    for (int ks = 0; ks < 2; ++ks) {
        bf16x8 a[2];
        #pragma unroll
        for (int m = 0; m < 2; ++m) {
            const float* xp = x + (((size_t)b * S_ + tok0 + m * 16 + lrow) * D_
                                   + ex * 64 + ks * 32 + lk8);
            float4 f0 = *(const float4*)xp;
            float4 f1 = *(const float4*)(xp + 4);
            bf16x8 av;
            av[0] = f2bf(f0.x); av[1] = f2bf(f0.y); av[2] = f2bf(f0.z); av[3] = f2bf(f0.w);
            av[4] = f2bf(f1.x); av[5] = f2bf(f1.y); av[6] = f2bf(f1.z); av[7] = f2bf(f1.w);
            a[m] = av;
        }
        #pragma unroll
        for (int nt = 0; nt < 8; ++nt) {
            int ntg = nhalf * 8 + nt;
            bf16x8 bf = *(const bf16x8*)(w1f + ((((size_t)(ex * 2 + ks) * 16 + ntg) * 64 + lane) << 3));
            acc1[0][nt] = __builtin_amdgcn_mfma_f32_16x16x32_bf16(a[0], bf, acc1[0][nt], 0, 0, 0);
            acc1[1][nt] = __builtin_amdgcn_mfma_f32_16x16x32_bf16(a[1], bf, acc1[1][nt], 0, 0, 0);
        }
    }

    #pragma unroll
    for (int nt = 0; nt < 8; ++nt) {
        int ncol = (nhalf * 8 + nt) * 16 + lrow;
        float bb = b1[ex * 256 + ncol];
        #pragma unroll
        for (int m = 0; m < 2; ++m) {
            int r0 = m * 16 + ((lane >> 4) << 2);
            #pragma unroll
            for (int r = 0; r < 4; ++r) {
                float v = acc1[m][nt][r] + bb;
                v = 0.5f * v * (1.0f + erff(v * 0.70710678118f));
                G[r0 + r][slot * 256 + ncol] = f2bf(v);
            }
        }
    }
    __syncthreads();

    f32x4 acc2[2][16];
    #pragma unroll
    for (int m = 0; m < 2; ++m)
        #pragma unroll
        for (int n = 0; n < 16; ++n) acc2[m][n] = (f32x4){0.f, 0.f, 0.f, 0.f};

    for (int ks = 0; ks < 16; ++ks) {
        int e  = (ks < 8) ? e0 : e1;
        int kg = e * 8 + (ks & 7);
        bf16x8 a0 = *(const bf16x8*)&G[lrow][ks * 32 + lk8];
        bf16x8 a1 = *(const bf16x8*)&G[16 + lrow][ks * 32 + lk8];
        #pragma unroll
        for (int nt = 0; nt < 16; ++nt) {
            int ntg = wid * 16 + nt;
            bf16x8 bf = *(const bf16x8*)(w2f + ((((size_t)kg * 64 + ntg) * 64 + lane) << 3));
            acc2[0][nt] = __builtin_amdgcn_mfma_f32_16x16x32_bf16(a0, bf, acc2[0][nt], 0, 0, 0);
            acc2[1][nt] = __builtin_amdgcn_mfma_f32_16x16x32_bf16(a1, bf, acc2[1][nt], 0, 0, 0);
        }
    }

    size_t obase = ((size_t)b * S_ + tok0) * D_;
    #pragma unroll
    for (int nt = 0; nt < 16; ++nt) {
        int d = wid * 256 + nt * 16 + lrow;
        float bb = b2[d];
        #pragma unroll
        for (int m = 0; m < 2; ++m) {
            int r0 = m * 16 + ((lane >> 4) << 2);
            #pragma unroll
            for (int r = 0; r < 4; ++r)
                out[obase + (size_t)(r0 + r) * D_ + d] = acc2[m][nt][r] + bb;
        }
    }
}

// ---------------------------------------------------------------------------
extern "C" void kernel_launch(void* const* d_in, const int* in_sizes, int n_in,
                              void* d_out, int out_size, void* d_ws, size_t ws_size,
                              hipStream_t stream) {
    const float* x   = (const float*)d_in[0];
    const float* wsw = (const float*)d_in[1];
    const float* bsw = (const float*)d_in[2];
    const float* w1  = (const float*)d_in[3];
    const float* b1  = (const float*)d_in[4];
    const float* w2  = (const float*)d_in[5];
    const float* b2  = (const float*)d_in[6];
    float* out = (float*)d_out;

    int*   experts  = (int*)d_ws;                                    // 64 B
    float* logits   = (float*)((char*)d_ws + 512);                   // 512 B
    float* partials = (float*)((char*)d_ws + 4096);                  // 8192*128*4 = 4 MB
    short* w1f = (short*)((char*)d_ws + 4096 + 4194304);             // 512 KB
    short* w2f = (short*)((char*)d_ws + 4096 + 4194304 + 524288);    // 8 MB

    router_kernel<<<NBLK_, 256, 0, stream>>>(x, wsw, partials);
    convert_w<<<2176, 256, 0, stream>>>(w1, w2, w1f, w2f);
    reduce_kernel<<<128, 256, 0, stream>>>(partials, logits);
    topk_kernel<<<1, 64, 0, stream>>>(logits, bsw, experts);
    mlp_kernel<<<512, 256, 0, stream>>>(x, experts, w1f, b1, w2f, b2, out);
}

// Round 13
// 131.568 us; speedup vs baseline: 1.2422x; 1.0489x over previous
//
#include <hip/hip_runtime.h>
#include <hip/hip_bf16.h>

#define B_  8
#define S_  2048
#define D_  1024
#define E_  16
#define SD_ 64
#define SH_ 256
#define H_  4096
#define R_  (D_ * S_)      // 2097152 rows of w_switch (MAX_SEQ == S)
#define NBLK_ 8192         // router blocks (burst-style: 256 rows/block)

typedef __attribute__((ext_vector_type(8))) short bf16x8;
typedef __attribute__((ext_vector_type(4))) float f32x4;

static __device__ __forceinline__ short f2bf(float f) {
    union { float f; unsigned u; } v; v.f = f;
    unsigned r = v.u + 0x7fffu + ((v.u >> 16) & 1u);   // RNE to bf16
    return (short)(r >> 16);
}

// ---------------------------------------------------------------------------
// Convert w1 [16][64][256] + w2 [4096][1024] fp32 -> MFMA B-fragment bf16.
// Blocks [0,128): w1; blocks [128,2176): w2.
// ---------------------------------------------------------------------------
__global__ void convert_w(const float* __restrict__ w1, const float* __restrict__ w2,
                          short* __restrict__ w1f, short* __restrict__ w2f) {
    int blk = blockIdx.x;
    if (blk < 128) {
        int t = blk * 256 + threadIdx.x;              // 32768 threads
        int lane = t & 63, ntile = (t >> 6) & 15, ks = (t >> 10) & 1, e = t >> 11;
        int k0 = ks * 32 + ((lane >> 4) << 3);
        int n  = (ntile << 4) + (lane & 15);
        const float* src = w1 + ((size_t)(e * 64 + k0) * 256 + n);
        bf16x8 o;
        #pragma unroll
        for (int j = 0; j < 8; ++j) o[j] = f2bf(src[(size_t)j * 256]);
        *(bf16x8*)(w1f + ((size_t)t << 3)) = o;
    } else {
        int t = (blk - 128) * 256 + threadIdx.x;      // 524288 threads
        int lane = t & 63, ntile = (t >> 6) & 63, kg = t >> 12;   // kg < 128
        int k0 = (kg << 5) + ((lane >> 4) << 3);
        int n  = (ntile << 4) + (lane & 15);
        const float* src = w2 + ((size_t)k0 * 1024 + n);
        bf16x8 o;
        #pragma unroll
        for (int j = 0; j < 8; ++j) o[j] = f2bf(src[(size_t)j * 1024]);
        *(bf16x8*)(w2f + ((size_t)t << 3)) = o;
    }
}

// ---------------------------------------------------------------------------
// Router, burst-style (R7 shape + contiguous 512-B partial writes):
// wave owns 64 rows; all 36 loads (4 w-float4 + 32 x-64B-lines) issue as one
// independent burst, then 128 FMAs, shuffle-reduce, one contiguous partial
// write per block. partials layout: [block(8192)][entry(128)]
// ---------------------------------------------------------------------------
__global__ __launch_bounds__(256, 4) void router_kernel(const float* __restrict__ x,
                                                        const float* __restrict__ wsw,
                                                        float* __restrict__ partials) {
    __shared__ float red[512];
    int tid = threadIdx.x;
    int wid = tid >> 6, lane = tid & 63;
    int q = lane & 3, rsub = lane >> 2;                // row within 16
    size_t wavebase = (((size_t)blockIdx.x << 2) + wid) << 6;   // 64 rows/wave
    const f32x4* wp = (const f32x4*)wsw + (wavebase << 2) + lane;

    // ---- burst loads: all independent ----
    f32x4 w0 = wp[0];
    f32x4 w1v = wp[64];
    f32x4 w2v = wp[128];
    f32x4 w3v = wp[192];
    float xv[4][8];
    #pragma unroll
    for (int b = 0; b < 8; ++b) {
        const float* xb = x + (size_t)b * R_ + wavebase + rsub;
        #pragma unroll
        for (int it = 0; it < 4; ++it)
            xv[it][b] = xb[it << 4];
    }

    // ---- compute ----
    float acc[8][4];
    #pragma unroll
    for (int b = 0; b < 8; ++b)
        #pragma unroll
        for (int j = 0; j < 4; ++j) acc[b][j] = 0.f;

    #define FMA4(W, IT)                                             \
        _Pragma("unroll")                                           \
        for (int b = 0; b < 8; ++b) {                               \
            float xs = xv[IT][b];                                   \
            acc[b][0] = fmaf(xs, (W)[0], acc[b][0]);                \
            acc[b][1] = fmaf(xs, (W)[1], acc[b][1]);                \
            acc[b][2] = fmaf(xs, (W)[2], acc[b][2]);                \
            acc[b][3] = fmaf(xs, (W)[3], acc[b][3]);                \
        }
    FMA4(w0, 0)
    FMA4(w1v, 1)
    FMA4(w2v, 2)
    FMA4(w3v, 3)
    #undef FMA4

    // reduce across the 16 lanes sharing q (xor 4,8,16,32)
    #pragma unroll
    for (int b = 0; b < 8; ++b)
        #pragma unroll
        for (int j = 0; j < 4; ++j) {
            float v = acc[b][j];
            v += __shfl_xor(v, 4);
            v += __shfl_xor(v, 8);
            v += __shfl_xor(v, 16);
            v += __shfl_xor(v, 32);
            acc[b][j] = v;
        }

    if (lane < 4) {
        #pragma unroll
        for (int b = 0; b < 8; ++b)
            #pragma unroll
            for (int j = 0; j < 4; ++j)
                red[(wid << 7) + b * 16 + q * 4 + j] = acc[b][j];
    }
    __syncthreads();
    if (tid < 128)
        partials[(size_t)blockIdx.x * 128 + tid] =
            red[tid] + red[128 + tid] + red[256 + tid] + red[384 + tid];
}

// ---------------------------------------------------------------------------
// Reduce stage 1: partials[8192][128] -> part2[128][128].
// Block j sums its 64 CONTIGUOUS rows with coalesced f32x4 sweeps
// (threads cover 8 rows x 32 col4-groups per pass), then folds the 8
// row-groups via shfl_xor(32) + LDS.
// ---------------------------------------------------------------------------
__global__ __launch_bounds__(256) void reduce_kernel(const float* __restrict__ partials,
                                                     float* __restrict__ part2) {
    __shared__ float sred[4][128];
    int j = blockIdx.x, tid = threadIdx.x;
    int col4 = tid & 31, rg = tid >> 5;               // col4-group, row-group
    const f32x4* p4 = (const f32x4*)partials;

    f32x4 acc = (f32x4){0.f, 0.f, 0.f, 0.f};
    #pragma unroll
    for (int p = 0; p < 8; ++p) {
        f32x4 v = p4[(size_t)(j * 64 + p * 8 + rg) * 32 + col4];
        acc[0] += v[0]; acc[1] += v[1]; acc[2] += v[2]; acc[3] += v[3];
    }
    #pragma unroll
    for (int k = 0; k < 4; ++k) acc[k] += __shfl_xor(acc[k], 32);

    int wid = tid >> 6, lane = tid & 63;
    if (lane < 32) {
        #pragma unroll
        for (int k = 0; k < 4; ++k) sred[wid][lane * 4 + k] = acc[k];
    }
    __syncthreads();
    if (tid < 128)
        part2[(size_t)j * 128 + tid] =
            sred[0][tid] + sred[1][tid] + sred[2][tid] + sred[3][tid];
}

// ---------------------------------------------------------------------------
// Reduce stage 2 (64 KB, L2-resident) + top-2 per batch, one dispatch.
// ---------------------------------------------------------------------------
__global__ __launch_bounds__(128) void topk_kernel(const float* __restrict__ part2,
                                                   const float* __restrict__ bsw,
                                                   int* __restrict__ experts) {
    __shared__ float vlog[128];
    int tid = threadIdx.x;                            // 128 threads
    float t = 0.f;
    #pragma unroll 8
    for (int j = 0; j < 128; ++j) t += part2[(size_t)j * 128 + tid];
    vlog[tid] = t + bsw[tid & 15];
    __syncthreads();
    if (tid < 8) {
        float v[16];
        #pragma unroll
        for (int e = 0; e < 16; ++e) v[e] = vlog[tid * 16 + e];
        int i0 = 0; float m0 = v[0];
        #pragma unroll
        for (int e = 1; e < 16; ++e) if (v[e] > m0) { m0 = v[e]; i0 = e; }
        int i1 = -1; float m1 = -3.4e38f;
        #pragma unroll
        for (int e = 0; e < 16; ++e) if (e != i0 && v[e] > m1) { m1 = v[e]; i1 = e; }
        experts[2 * tid]     = i0;
        experts[2 * tid + 1] = i1;
    }
}

// ---------------------------------------------------------------------------
// Fused expert MLP — exact R8 version (verified fast, absmax 0.0078):
// 32 tokens/block, 512 blocks, each w2f fragment load feeds 2 MFMAs.
// ---------------------------------------------------------------------------
__global__ __launch_bounds__(256, 2) void mlp_kernel(
        const float* __restrict__ x, const int* __restrict__ experts,
        const short* __restrict__ w1f, const float* __restrict__ b1,
        const short* __restrict__ w2f, const float* __restrict__ b2,
        float* __restrict__ out) {
    __shared__ short G[32][520];

    int blk  = blockIdx.x;
    int b    = blk & 7;            // XCD-friendly: batch = blk%8
    int tok0 = (blk >> 3) << 5;
    int e0 = experts[2 * b], e1 = experts[2 * b + 1];
    int tid = threadIdx.x;
    int wid = tid >> 6, lane = tid & 63;
    int slot  = wid >> 1;
    int ex    = slot ? e1 : e0;
    int nhalf = wid & 1;
    int lrow = lane & 15, lk8 = (lane >> 4) << 3;

    f32x4 acc1[2][8];
    #pragma unroll
    for (int m = 0; m < 2; ++m)
        #pragma unroll
        for (int n = 0; n < 8; ++n) acc1[m][n] = (f32x4){0.f, 0.f, 0.f, 0.f};

    #pragma unroll
    for (int ks = 0; ks < 2; ++ks) {
        bf16x8 a[2];
        #pragma unroll
        for (int m = 0; m < 2; ++m) {
            const float* xp = x + (((size_t)b * S_ + tok0 + m * 16 + lrow) * D_
                                   + ex * 64 + ks * 32 + lk8);
            float4 f0 = *(const float4*)xp;
            float4 f1 = *(const float4*)(xp + 4);
            bf16x8 av;
            av[0] = f2bf(f0.x); av[1] = f2bf(f0.y); av[2] = f2bf(f0.z); av[3] = f2bf(f0.w);
            av[4] = f2bf(f1.x); av[5] = f2bf(f1.y); av[6] = f2bf(f1.z); av[7] = f2bf(f1.w);
            a[m] = av;
        }
        #pragma unroll
        for (int nt = 0; nt < 8; ++nt) {
            int ntg = nhalf * 8 + nt;
            bf16x8 bf = *(const bf16x8*)(w1f + ((((size_t)(ex * 2 + ks) * 16 + ntg) * 64 + lane) << 3));
            acc1[0][nt] = __builtin_amdgcn_mfma_f32_16x16x32_bf16(a[0], bf, acc1[0][nt], 0, 0, 0);
            acc1[1][nt] = __builtin_amdgcn_mfma_f32_16x16x32_bf16(a[1], bf, acc1[1][nt], 0, 0, 0);
        }
    }

    #pragma unroll
    for (int nt = 0; nt < 8; ++nt) {
        int ncol = (nhalf * 8 + nt) * 16 + lrow;
        float bb = b1[ex * 256 + ncol];
        #pragma unroll
        for (int m = 0; m < 2; ++m) {
            int r0 = m * 16 + ((lane >> 4) << 2);
            #pragma unroll
            for (int r = 0; r < 4; ++r) {
                float v = acc1[m][nt][r] + bb;
                v = 0.5f * v * (1.0f + erff(v * 0.70710678118f));
                G[r0 + r][slot * 256 + ncol] = f2bf(v);
            }
        }
    }
    __syncthreads();

    f32x4 acc2[2][16];
    #pragma unroll
    for (int m = 0; m < 2; ++m)
        #pragma unroll
        for (int n = 0; n < 16; ++n) acc2[m][n] = (f32x4){0.f, 0.f, 0.f, 0.f};

    for (int ks = 0; ks < 16; ++ks) {
        int e  = (ks < 8) ? e0 : e1;
        int kg = e * 8 + (ks & 7);
        bf16x8 a0 = *(const bf16x8*)&G[lrow][ks * 32 + lk8];
        bf16x8 a1 = *(const bf16x8*)&G[16 + lrow][ks * 32 + lk8];
        #pragma unroll
        for (int nt = 0; nt < 16; ++nt) {
            int ntg = wid * 16 + nt;
            bf16x8 bf = *(const bf16x8*)(w2f + ((((size_t)kg * 64 + ntg) * 64 + lane) << 3));
            acc2[0][nt] = __builtin_amdgcn_mfma_f32_16x16x32_bf16(a0, bf, acc2[0][nt], 0, 0, 0);
            acc2[1][nt] = __builtin_amdgcn_mfma_f32_16x16x32_bf16(a1, bf, acc2[1][nt], 0, 0, 0);
        }
    }

    size_t obase = ((size_t)b * S_ + tok0) * D_;
    #pragma unroll
    for (int nt = 0; nt < 16; ++nt) {
        int d = wid * 256 + nt * 16 + lrow;
        float bb = b2[d];
        #pragma unroll
        for (int m = 0; m < 2; ++m) {
            int r0 = m * 16 + ((lane >> 4) << 2);
            #pragma unroll
            for (int r = 0; r < 4; ++r)
                out[obase + (size_t)(r0 + r) * D_ + d] = acc2[m][nt][r] + bb;
        }
    }
}

// ---------------------------------------------------------------------------
extern "C" void kernel_launch(void* const* d_in, const int* in_sizes, int n_in,
                              void* d_out, int out_size, void* d_ws, size_t ws_size,
                              hipStream_t stream) {
    const float* x   = (const float*)d_in[0];
    const float* wsw = (const float*)d_in[1];
    const float* bsw = (const float*)d_in[2];
    const float* w1  = (const float*)d_in[3];
    const float* b1  = (const float*)d_in[4];
    const float* w2  = (const float*)d_in[5];
    const float* b2  = (const float*)d_in[6];
    float* out = (float*)d_out;

    int*   experts  = (int*)d_ws;                                    // 64 B
    float* partials = (float*)((char*)d_ws + 4096);                  // 8192*128*4 = 4 MB
    float* part2    = (float*)((char*)d_ws + 4096 + 4194304);        // 128*128*4 = 64 KB
    short* w1f = (short*)((char*)d_ws + 4096 + 4194304 + 65536);             // 512 KB
    short* w2f = (short*)((char*)d_ws + 4096 + 4194304 + 65536 + 524288);    // 8 MB

    router_kernel<<<NBLK_, 256, 0, stream>>>(x, wsw, partials);
    convert_w<<<2176, 256, 0, stream>>>(w1, w2, w1f, w2f);
    reduce_kernel<<<128, 256, 0, stream>>>(partials, part2);
    topk_kernel<<<1, 128, 0, stream>>>(part2, bsw, experts);
    mlp_kernel<<<512, 256, 0, stream>>>(x, experts, w1f, b1, w2f, b2, out);
}

// Round 14
// 115.083 us; speedup vs baseline: 1.4201x; 1.1432x over previous
//
#include <hip/hip_runtime.h>
#include <hip/hip_bf16.h>

#define B_  8
#define S_  2048
#define D_  1024
#define E_  16
#define SD_ 64
#define SH_ 256
#define H_  4096
#define R_  (D_ * S_)      // 2097152 rows of w_switch (MAX_SEQ == S)
#define NBLK_ 8192         // router blocks (burst-style: 256 rows/block)

typedef __attribute__((ext_vector_type(8))) short bf16x8;
typedef __attribute__((ext_vector_type(4))) float f32x4;

static __device__ __forceinline__ short f2bf(float f) {
    union { float f; unsigned u; } v; v.f = f;
    unsigned r = v.u + 0x7fffu + ((v.u >> 16) & 1u);   // RNE to bf16
    return (short)(r >> 16);
}

// ---------------------------------------------------------------------------
// Convert w1 [16][64][256] + w2 [4096][1024] fp32 -> MFMA B-fragment bf16.
// Blocks [0,128): w1; blocks [128,2176): w2.
// ---------------------------------------------------------------------------
__global__ void convert_w(const float* __restrict__ w1, const float* __restrict__ w2,
                          short* __restrict__ w1f, short* __restrict__ w2f) {
    int blk = blockIdx.x;
    if (blk < 128) {
        int t = blk * 256 + threadIdx.x;              // 32768 threads
        int lane = t & 63, ntile = (t >> 6) & 15, ks = (t >> 10) & 1, e = t >> 11;
        int k0 = ks * 32 + ((lane >> 4) << 3);
        int n  = (ntile << 4) + (lane & 15);
        const float* src = w1 + ((size_t)(e * 64 + k0) * 256 + n);
        bf16x8 o;
        #pragma unroll
        for (int j = 0; j < 8; ++j) o[j] = f2bf(src[(size_t)j * 256]);
        *(bf16x8*)(w1f + ((size_t)t << 3)) = o;
    } else {
        int t = (blk - 128) * 256 + threadIdx.x;      // 524288 threads
        int lane = t & 63, ntile = (t >> 6) & 63, kg = t >> 12;   // kg < 128
        int k0 = (kg << 5) + ((lane >> 4) << 3);
        int n  = (ntile << 4) + (lane & 15);
        const float* src = w2 + ((size_t)k0 * 1024 + n);
        bf16x8 o;
        #pragma unroll
        for (int j = 0; j < 8; ++j) o[j] = f2bf(src[(size_t)j * 1024]);
        *(bf16x8*)(w2f + ((size_t)t << 3)) = o;
    }
}

// ---------------------------------------------------------------------------
// Router, burst-style (measured wall 77.7 µs across 7 structures — UNCHANGED)
// ---------------------------------------------------------------------------
__global__ __launch_bounds__(256, 4) void router_kernel(const float* __restrict__ x,
                                                        const float* __restrict__ wsw,
                                                        float* __restrict__ partials) {
    __shared__ float red[512];
    int tid = threadIdx.x;
    int wid = tid >> 6, lane = tid & 63;
    int q = lane & 3, rsub = lane >> 2;                // row within 16
    size_t wavebase = (((size_t)blockIdx.x << 2) + wid) << 6;   // 64 rows/wave
    const f32x4* wp = (const f32x4*)wsw + (wavebase << 2) + lane;

    f32x4 w0 = wp[0];
    f32x4 w1v = wp[64];
    f32x4 w2v = wp[128];
    f32x4 w3v = wp[192];
    float xv[4][8];
    #pragma unroll
    for (int b = 0; b < 8; ++b) {
        const float* xb = x + (size_t)b * R_ + wavebase + rsub;
        #pragma unroll
        for (int it = 0; it < 4; ++it)
            xv[it][b] = xb[it << 4];
    }

    float acc[8][4];
    #pragma unroll
    for (int b = 0; b < 8; ++b)
        #pragma unroll
        for (int j = 0; j < 4; ++j) acc[b][j] = 0.f;

    #define FMA4(W, IT)                                             \
        _Pragma("unroll")                                           \
        for (int b = 0; b < 8; ++b) {                               \
            float xs = xv[IT][b];                                   \
            acc[b][0] = fmaf(xs, (W)[0], acc[b][0]);                \
            acc[b][1] = fmaf(xs, (W)[1], acc[b][1]);                \
            acc[b][2] = fmaf(xs, (W)[2], acc[b][2]);                \
            acc[b][3] = fmaf(xs, (W)[3], acc[b][3]);                \
        }
    FMA4(w0, 0)
    FMA4(w1v, 1)
    FMA4(w2v, 2)
    FMA4(w3v, 3)
    #undef FMA4

    #pragma unroll
    for (int b = 0; b < 8; ++b)
        #pragma unroll
        for (int j = 0; j < 4; ++j) {
            float v = acc[b][j];
            v += __shfl_xor(v, 4);
            v += __shfl_xor(v, 8);
            v += __shfl_xor(v, 16);
            v += __shfl_xor(v, 32);
            acc[b][j] = v;
        }

    if (lane < 4) {
        #pragma unroll
        for (int b = 0; b < 8; ++b)
            #pragma unroll
            for (int j = 0; j < 4; ++j)
                red[(wid << 7) + b * 16 + q * 4 + j] = acc[b][j];
    }
    __syncthreads();
    if (tid < 128)
        partials[(size_t)blockIdx.x * 128 + tid] =
            red[tid] + red[128 + tid] + red[256 + tid] + red[384 + tid];
}

// ---------------------------------------------------------------------------
// Reduce stage 1: partials[8192][128] -> part2[128][128] (coalesced).
// ---------------------------------------------------------------------------
__global__ __launch_bounds__(256) void reduce_kernel(const float* __restrict__ partials,
                                                     float* __restrict__ part2) {
    __shared__ float sred[4][128];
    int j = blockIdx.x, tid = threadIdx.x;
    int col4 = tid & 31, rg = tid >> 5;
    const f32x4* p4 = (const f32x4*)partials;

    f32x4 acc = (f32x4){0.f, 0.f, 0.f, 0.f};
    #pragma unroll
    for (int p = 0; p < 8; ++p) {
        f32x4 v = p4[(size_t)(j * 64 + p * 8 + rg) * 32 + col4];
        acc[0] += v[0]; acc[1] += v[1]; acc[2] += v[2]; acc[3] += v[3];
    }
    #pragma unroll
    for (int k = 0; k < 4; ++k) acc[k] += __shfl_xor(acc[k], 32);

    int wid = tid >> 6, lane = tid & 63;
    if (lane < 32) {
        #pragma unroll
        for (int k = 0; k < 4; ++k) sred[wid][lane * 4 + k] = acc[k];
    }
    __syncthreads();
    if (tid < 128)
        part2[(size_t)j * 128 + tid] =
            sred[0][tid] + sred[1][tid] + sred[2][tid] + sred[3][tid];
}

// ---------------------------------------------------------------------------
// Reduce stage 2 + top-2 per batch.
// ---------------------------------------------------------------------------
__global__ __launch_bounds__(128) void topk_kernel(const float* __restrict__ part2,
                                                   const float* __restrict__ bsw,
                                                   int* __restrict__ experts) {
    __shared__ float vlog[128];
    int tid = threadIdx.x;
    float t = 0.f;
    #pragma unroll 8
    for (int j = 0; j < 128; ++j) t += part2[(size_t)j * 128 + tid];
    vlog[tid] = t + bsw[tid & 15];
    __syncthreads();
    if (tid < 8) {
        float v[16];
        #pragma unroll
        for (int e = 0; e < 16; ++e) v[e] = vlog[tid * 16 + e];
        int i0 = 0; float m0 = v[0];
        #pragma unroll
        for (int e = 1; e < 16; ++e) if (v[e] > m0) { m0 = v[e]; i0 = e; }
        int i1 = -1; float m1 = -3.4e38f;
        #pragma unroll
        for (int e = 0; e < 16; ++e) if (e != i0 && v[e] > m1) { m1 = v[e]; i1 = e; }
        experts[2 * tid]     = i0;
        experts[2 * tid + 1] = i1;
    }
}

// ---------------------------------------------------------------------------
// Fused expert MLP — same 32-token tile / same math, restructured to
// 8 waves (512 threads): GEMM1 wave = (slot, nhalf, mh); GEMM2 wave owns a
// 128-col N-slice (acc2 = 64 VGPR). 2 blocks/CU -> 16 waves/CU (2x TLP)
// to hide the L2 latency of w2f fragment loads.
// ---------------------------------------------------------------------------
__global__ __launch_bounds__(512, 4) void mlp_kernel(
        const float* __restrict__ x, const int* __restrict__ experts,
        const short* __restrict__ w1f, const float* __restrict__ b1,
        const short* __restrict__ w2f, const float* __restrict__ b2,
        float* __restrict__ out) {
    __shared__ short G[32][520];

    int blk  = blockIdx.x;
    int b    = blk & 7;            // XCD-friendly: batch = blk%8
    int tok0 = (blk >> 3) << 5;
    int e0 = experts[2 * b], e1 = experts[2 * b + 1];
    int tid = threadIdx.x;
    int wid = tid >> 6, lane = tid & 63;          // wid in [0,8)
    int lrow = lane & 15, lk8 = (lane >> 4) << 3;
    int r0 = (lane >> 4) << 2;

    // ---- GEMM1: wave = (slot = wid>>2, nhalf = (wid>>1)&1, mh = wid&1) ----
    {
        int slot  = wid >> 2;
        int ex    = slot ? e1 : e0;
        int nhalf = (wid >> 1) & 1;
        int mh    = wid & 1;

        f32x4 acc1[8];
        #pragma unroll
        for (int n = 0; n < 8; ++n) acc1[n] = (f32x4){0.f, 0.f, 0.f, 0.f};

        #pragma unroll
        for (int ks = 0; ks < 2; ++ks) {
            const float* xp = x + (((size_t)b * S_ + tok0 + mh * 16 + lrow) * D_
                                   + ex * 64 + ks * 32 + lk8);
            float4 f0 = *(const float4*)xp;
            float4 f1 = *(const float4*)(xp + 4);
            bf16x8 a;
            a[0] = f2bf(f0.x); a[1] = f2bf(f0.y); a[2] = f2bf(f0.z); a[3] = f2bf(f0.w);
            a[4] = f2bf(f1.x); a[5] = f2bf(f1.y); a[6] = f2bf(f1.z); a[7] = f2bf(f1.w);
            #pragma unroll
            for (int nt = 0; nt < 8; ++nt) {
                int ntg = nhalf * 8 + nt;
                bf16x8 bf = *(const bf16x8*)(w1f + ((((size_t)(ex * 2 + ks) * 16 + ntg) * 64 + lane) << 3));
                acc1[nt] = __builtin_amdgcn_mfma_f32_16x16x32_bf16(a, bf, acc1[nt], 0, 0, 0);
            }
        }

        #pragma unroll
        for (int nt = 0; nt < 8; ++nt) {
            int ncol = (nhalf * 8 + nt) * 16 + lrow;
            float bb = b1[ex * 256 + ncol];
            #pragma unroll
            for (int r = 0; r < 4; ++r) {
                float v = acc1[nt][r] + bb;
                v = 0.5f * v * (1.0f + erff(v * 0.70710678118f));
                G[mh * 16 + r0 + r][slot * 256 + ncol] = f2bf(v);
            }
        }
    }
    __syncthreads();

    // ---- GEMM2: wave wid owns cols [wid*128, wid*128+128) ----
    f32x4 acc2[2][8];
    #pragma unroll
    for (int m = 0; m < 2; ++m)
        #pragma unroll
        for (int n = 0; n < 8; ++n) acc2[m][n] = (f32x4){0.f, 0.f, 0.f, 0.f};

    for (int ks = 0; ks < 16; ++ks) {
        int e  = (ks < 8) ? e0 : e1;
        int kg = e * 8 + (ks & 7);
        bf16x8 a0 = *(const bf16x8*)&G[lrow][ks * 32 + lk8];
        bf16x8 a1 = *(const bf16x8*)&G[16 + lrow][ks * 32 + lk8];
        #pragma unroll
        for (int nt = 0; nt < 8; ++nt) {
            int ntg = wid * 8 + nt;
            bf16x8 bf = *(const bf16x8*)(w2f + ((((size_t)kg * 64 + ntg) * 64 + lane) << 3));
            acc2[0][nt] = __builtin_amdgcn_mfma_f32_16x16x32_bf16(a0, bf, acc2[0][nt], 0, 0, 0);
            acc2[1][nt] = __builtin_amdgcn_mfma_f32_16x16x32_bf16(a1, bf, acc2[1][nt], 0, 0, 0);
        }
    }

    size_t obase = ((size_t)b * S_ + tok0) * D_;
    #pragma unroll
    for (int nt = 0; nt < 8; ++nt) {
        int d = wid * 128 + nt * 16 + lrow;
        float bb = b2[d];
        #pragma unroll
        for (int m = 0; m < 2; ++m) {
            int rr = m * 16 + r0;
            #pragma unroll
            for (int r = 0; r < 4; ++r)
                out[obase + (size_t)(rr + r) * D_ + d] = acc2[m][nt][r] + bb;
        }
    }
}

// ---------------------------------------------------------------------------
extern "C" void kernel_launch(void* const* d_in, const int* in_sizes, int n_in,
                              void* d_out, int out_size, void* d_ws, size_t ws_size,
                              hipStream_t stream) {
    const float* x   = (const float*)d_in[0];
    const float* wsw = (const float*)d_in[1];
    const float* bsw = (const float*)d_in[2];
    const float* w1  = (const float*)d_in[3];
    const float* b1  = (const float*)d_in[4];
    const float* w2  = (const float*)d_in[5];
    const float* b2  = (const float*)d_in[6];
    float* out = (float*)d_out;

    int*   experts  = (int*)d_ws;                                    // 64 B
    float* partials = (float*)((char*)d_ws + 4096);                  // 8192*128*4 = 4 MB
    float* part2    = (float*)((char*)d_ws + 4096 + 4194304);        // 64 KB
    short* w1f = (short*)((char*)d_ws + 4096 + 4194304 + 65536);             // 512 KB
    short* w2f = (short*)((char*)d_ws + 4096 + 4194304 + 65536 + 524288);    // 8 MB

    router_kernel<<<NBLK_, 256, 0, stream>>>(x, wsw, partials);
    convert_w<<<2176, 256, 0, stream>>>(w1, w2, w1f, w2f);
    reduce_kernel<<<128, 256, 0, stream>>>(partials, part2);
    topk_kernel<<<1, 128, 0, stream>>>(part2, bsw, experts);
    mlp_kernel<<<512, 512, 0, stream>>>(x, experts, w1f, b1, w2f, b2, out);
}

// Round 15
// 110.417 us; speedup vs baseline: 1.4802x; 1.0423x over previous
//
#include <hip/hip_runtime.h>
#include <hip/hip_bf16.h>

#define B_  8
#define S_  2048
#define D_  1024
#define E_  16
#define SD_ 64
#define SH_ 256
#define H_  4096
#define R_  (D_ * S_)      // 2097152 rows of w_switch (MAX_SEQ == S)
#define NBLK_ 8192         // router blocks (burst-style: 256 rows/block)
#define NCVT_ 2176         // convert blocks appended to the router grid

typedef __attribute__((ext_vector_type(8))) short bf16x8;
typedef __attribute__((ext_vector_type(4))) float f32x4;

static __device__ __forceinline__ short f2bf(float f) {
    union { float f; unsigned u; } v; v.f = f;
    unsigned r = v.u + 0x7fffu + ((v.u >> 16) & 1u);   // RNE to bf16
    return (short)(r >> 16);
}

// ---------------------------------------------------------------------------
// Fused router + weight-convert, one dispatch. Blocks [0,NBLK_): router
// (measured wall 77.7 µs, latency-bound, 34% occupancy); blocks
// [NBLK_, NBLK_+NCVT_): convert — backfills CU slots as router blocks drain,
// hiding convert's ~8-10 µs under the router tail.
// ---------------------------------------------------------------------------
__global__ __launch_bounds__(256, 4) void router_conv_kernel(
        const float* __restrict__ x, const float* __restrict__ wsw,
        const float* __restrict__ w1, const float* __restrict__ w2,
        float* __restrict__ partials, short* __restrict__ w1f,
        short* __restrict__ w2f) {
    if (blockIdx.x >= NBLK_) {
        int blk = blockIdx.x - NBLK_;
        if (blk < 128) {
            // w1 [16][64][256] -> MFMA B-fragment bf16
            int t = blk * 256 + threadIdx.x;              // 32768 threads
            int lane = t & 63, ntile = (t >> 6) & 15, ks = (t >> 10) & 1, e = t >> 11;
            int k0 = ks * 32 + ((lane >> 4) << 3);
            int n  = (ntile << 4) + (lane & 15);
            const float* src = w1 + ((size_t)(e * 64 + k0) * 256 + n);
            bf16x8 o;
            #pragma unroll
            for (int j = 0; j < 8; ++j) o[j] = f2bf(src[(size_t)j * 256]);
            *(bf16x8*)(w1f + ((size_t)t << 3)) = o;
        } else {
            // w2 [4096][1024] -> fragment bf16
            int t = (blk - 128) * 256 + threadIdx.x;      // 524288 threads
            int lane = t & 63, ntile = (t >> 6) & 63, kg = t >> 12;   // kg < 128
            int k0 = (kg << 5) + ((lane >> 4) << 3);
            int n  = (ntile << 4) + (lane & 15);
            const float* src = w2 + ((size_t)k0 * 1024 + n);
            bf16x8 o;
            #pragma unroll
            for (int j = 0; j < 8; ++j) o[j] = f2bf(src[(size_t)j * 1024]);
            *(bf16x8*)(w2f + ((size_t)t << 3)) = o;
        }
        return;
    }

    // ---- router: burst-style, wave owns 64 rows ----
    __shared__ float red[512];
    int tid = threadIdx.x;
    int wid = tid >> 6, lane = tid & 63;
    int q = lane & 3, rsub = lane >> 2;                // row within 16
    size_t wavebase = (((size_t)blockIdx.x << 2) + wid) << 6;   // 64 rows/wave
    const f32x4* wp = (const f32x4*)wsw + (wavebase << 2) + lane;

    f32x4 w0 = wp[0];
    f32x4 w1v = wp[64];
    f32x4 w2v = wp[128];
    f32x4 w3v = wp[192];
    float xv[4][8];
    #pragma unroll
    for (int b = 0; b < 8; ++b) {
        const float* xb = x + (size_t)b * R_ + wavebase + rsub;
        #pragma unroll
        for (int it = 0; it < 4; ++it)
            xv[it][b] = xb[it << 4];
    }

    float acc[8][4];
    #pragma unroll
    for (int b = 0; b < 8; ++b)
        #pragma unroll
        for (int j = 0; j < 4; ++j) acc[b][j] = 0.f;

    #define FMA4(W, IT)                                             \
        _Pragma("unroll")                                           \
        for (int b = 0; b < 8; ++b) {                               \
            float xs = xv[IT][b];                                   \
            acc[b][0] = fmaf(xs, (W)[0], acc[b][0]);                \
            acc[b][1] = fmaf(xs, (W)[1], acc[b][1]);                \
            acc[b][2] = fmaf(xs, (W)[2], acc[b][2]);                \
            acc[b][3] = fmaf(xs, (W)[3], acc[b][3]);                \
        }
    FMA4(w0, 0)
    FMA4(w1v, 1)
    FMA4(w2v, 2)
    FMA4(w3v, 3)
    #undef FMA4

    #pragma unroll
    for (int b = 0; b < 8; ++b)
        #pragma unroll
        for (int j = 0; j < 4; ++j) {
            float v = acc[b][j];
            v += __shfl_xor(v, 4);
            v += __shfl_xor(v, 8);
            v += __shfl_xor(v, 16);
            v += __shfl_xor(v, 32);
            acc[b][j] = v;
        }

    if (lane < 4) {
        #pragma unroll
        for (int b = 0; b < 8; ++b)
            #pragma unroll
            for (int j = 0; j < 4; ++j)
                red[(wid << 7) + b * 16 + q * 4 + j] = acc[b][j];
    }
    __syncthreads();
    if (tid < 128)
        partials[(size_t)blockIdx.x * 128 + tid] =
            red[tid] + red[128 + tid] + red[256 + tid] + red[384 + tid];
}

// ---------------------------------------------------------------------------
// Reduce stage 1: partials[8192][128] -> part2[128][128] (coalesced).
// ---------------------------------------------------------------------------
__global__ __launch_bounds__(256) void reduce_kernel(const float* __restrict__ partials,
                                                     float* __restrict__ part2) {
    __shared__ float sred[4][128];
    int j = blockIdx.x, tid = threadIdx.x;
    int col4 = tid & 31, rg = tid >> 5;
    const f32x4* p4 = (const f32x4*)partials;

    f32x4 acc = (f32x4){0.f, 0.f, 0.f, 0.f};
    #pragma unroll
    for (int p = 0; p < 8; ++p) {
        f32x4 v = p4[(size_t)(j * 64 + p * 8 + rg) * 32 + col4];
        acc[0] += v[0]; acc[1] += v[1]; acc[2] += v[2]; acc[3] += v[3];
    }
    #pragma unroll
    for (int k = 0; k < 4; ++k) acc[k] += __shfl_xor(acc[k], 32);

    int wid = tid >> 6, lane = tid & 63;
    if (lane < 32) {
        #pragma unroll
        for (int k = 0; k < 4; ++k) sred[wid][lane * 4 + k] = acc[k];
    }
    __syncthreads();
    if (tid < 128)
        part2[(size_t)j * 128 + tid] =
            sred[0][tid] + sred[1][tid] + sred[2][tid] + sred[3][tid];
}

// ---------------------------------------------------------------------------
// Reduce stage 2 + top-2 per batch.
// ---------------------------------------------------------------------------
__global__ __launch_bounds__(128) void topk_kernel(const float* __restrict__ part2,
                                                   const float* __restrict__ bsw,
                                                   int* __restrict__ experts) {
    __shared__ float vlog[128];
    int tid = threadIdx.x;
    float t = 0.f;
    #pragma unroll 8
    for (int j = 0; j < 128; ++j) t += part2[(size_t)j * 128 + tid];
    vlog[tid] = t + bsw[tid & 15];
    __syncthreads();
    if (tid < 8) {
        float v[16];
        #pragma unroll
        for (int e = 0; e < 16; ++e) v[e] = vlog[tid * 16 + e];
        int i0 = 0; float m0 = v[0];
        #pragma unroll
        for (int e = 1; e < 16; ++e) if (v[e] > m0) { m0 = v[e]; i0 = e; }
        int i1 = -1; float m1 = -3.4e38f;
        #pragma unroll
        for (int e = 0; e < 16; ++e) if (e != i0 && v[e] > m1) { m1 = v[e]; i1 = e; }
        experts[2 * tid]     = i0;
        experts[2 * tid + 1] = i1;
    }
}

// ---------------------------------------------------------------------------
// Fused expert MLP — verified R14 8-wave version (total −16.5 µs vs 4-wave).
// ---------------------------------------------------------------------------
__global__ __launch_bounds__(512, 4) void mlp_kernel(
        const float* __restrict__ x, const int* __restrict__ experts,
        const short* __restrict__ w1f, const float* __restrict__ b1,
        const short* __restrict__ w2f, const float* __restrict__ b2,
        float* __restrict__ out) {
    __shared__ short G[32][520];

    int blk  = blockIdx.x;
    int b    = blk & 7;            // XCD-friendly: batch = blk%8
    int tok0 = (blk >> 3) << 5;
    int e0 = experts[2 * b], e1 = experts[2 * b + 1];
    int tid = threadIdx.x;
    int wid = tid >> 6, lane = tid & 63;          // wid in [0,8)
    int lrow = lane & 15, lk8 = (lane >> 4) << 3;
    int r0 = (lane >> 4) << 2;

    // ---- GEMM1: wave = (slot = wid>>2, nhalf = (wid>>1)&1, mh = wid&1) ----
    {
        int slot  = wid >> 2;
        int ex    = slot ? e1 : e0;
        int nhalf = (wid >> 1) & 1;
        int mh    = wid & 1;

        f32x4 acc1[8];
        #pragma unroll
        for (int n = 0; n < 8; ++n) acc1[n] = (f32x4){0.f, 0.f, 0.f, 0.f};

        #pragma unroll
        for (int ks = 0; ks < 2; ++ks) {
            const float* xp = x + (((size_t)b * S_ + tok0 + mh * 16 + lrow) * D_
                                   + ex * 64 + ks * 32 + lk8);
            float4 f0 = *(const float4*)xp;
            float4 f1 = *(const float4*)(xp + 4);
            bf16x8 a;
            a[0] = f2bf(f0.x); a[1] = f2bf(f0.y); a[2] = f2bf(f0.z); a[3] = f2bf(f0.w);
            a[4] = f2bf(f1.x); a[5] = f2bf(f1.y); a[6] = f2bf(f1.z); a[7] = f2bf(f1.w);
            #pragma unroll
            for (int nt = 0; nt < 8; ++nt) {
                int ntg = nhalf * 8 + nt;
                bf16x8 bf = *(const bf16x8*)(w1f + ((((size_t)(ex * 2 + ks) * 16 + ntg) * 64 + lane) << 3));
                acc1[nt] = __builtin_amdgcn_mfma_f32_16x16x32_bf16(a, bf, acc1[nt], 0, 0, 0);
            }
        }

        #pragma unroll
        for (int nt = 0; nt < 8; ++nt) {
            int ncol = (nhalf * 8 + nt) * 16 + lrow;
            float bb = b1[ex * 256 + ncol];
            #pragma unroll
            for (int r = 0; r < 4; ++r) {
                float v = acc1[nt][r] + bb;
                v = 0.5f * v * (1.0f + erff(v * 0.70710678118f));
                G[mh * 16 + r0 + r][slot * 256 + ncol] = f2bf(v);
            }
        }
    }
    __syncthreads();

    // ---- GEMM2: wave wid owns cols [wid*128, wid*128+128) ----
    f32x4 acc2[2][8];
    #pragma unroll
    for (int m = 0; m < 2; ++m)
        #pragma unroll
        for (int n = 0; n < 8; ++n) acc2[m][n] = (f32x4){0.f, 0.f, 0.f, 0.f};

    for (int ks = 0; ks < 16; ++ks) {
        int e  = (ks < 8) ? e0 : e1;
        int kg = e * 8 + (ks & 7);
        bf16x8 a0 = *(const bf16x8*)&G[lrow][ks * 32 + lk8];
        bf16x8 a1 = *(const bf16x8*)&G[16 + lrow][ks * 32 + lk8];
        #pragma unroll
        for (int nt = 0; nt < 8; ++nt) {
            int ntg = wid * 8 + nt;
            bf16x8 bf = *(const bf16x8*)(w2f + ((((size_t)kg * 64 + ntg) * 64 + lane) << 3));
            acc2[0][nt] = __builtin_amdgcn_mfma_f32_16x16x32_bf16(a0, bf, acc2[0][nt], 0, 0, 0);
            acc2[1][nt] = __builtin_amdgcn_mfma_f32_16x16x32_bf16(a1, bf, acc2[1][nt], 0, 0, 0);
        }
    }

    size_t obase = ((size_t)b * S_ + tok0) * D_;
    #pragma unroll
    for (int nt = 0; nt < 8; ++nt) {
        int d = wid * 128 + nt * 16 + lrow;
        float bb = b2[d];
        #pragma unroll
        for (int m = 0; m < 2; ++m) {
            int rr = m * 16 + r0;
            #pragma unroll
            for (int r = 0; r < 4; ++r)
                out[obase + (size_t)(rr + r) * D_ + d] = acc2[m][nt][r] + bb;
        }
    }
}

// ---------------------------------------------------------------------------
extern "C" void kernel_launch(void* const* d_in, const int* in_sizes, int n_in,
                              void* d_out, int out_size, void* d_ws, size_t ws_size,
                              hipStream_t stream) {
    const float* x   = (const float*)d_in[0];
    const float* wsw = (const float*)d_in[1];
    const float* bsw = (const float*)d_in[2];
    const float* w1  = (const float*)d_in[3];
    const float* b1  = (const float*)d_in[4];
    const float* w2  = (const float*)d_in[5];
    const float* b2  = (const float*)d_in[6];
    float* out = (float*)d_out;

    int*   experts  = (int*)d_ws;                                    // 64 B
    float* partials = (float*)((char*)d_ws + 4096);                  // 8192*128*4 = 4 MB
    float* part2    = (float*)((char*)d_ws + 4096 + 4194304);        // 64 KB
    short* w1f = (short*)((char*)d_ws + 4096 + 4194304 + 65536);             // 512 KB
    short* w2f = (short*)((char*)d_ws + 4096 + 4194304 + 65536 + 524288);    // 8 MB

    router_conv_kernel<<<NBLK_ + NCVT_, 256, 0, stream>>>(x, wsw, w1, w2,
                                                          partials, w1f, w2f);
    reduce_kernel<<<128, 256, 0, stream>>>(partials, part2);
    topk_kernel<<<1, 128, 0, stream>>>(part2, bsw, experts);
    mlp_kernel<<<512, 512, 0, stream>>>(x, experts, w1f, b1, w2f, b2, out);
}